// Round 18
// baseline (214.157 us; speedup 1.0000x reference)
//
#include <hip/hip_runtime.h>
#include <hip/hip_bf16.h>
#include <math.h>

#define BATCH 64
#define HH 56
#define CH 96
#define HEADS 3
#define WIN 7
#define SHIFT 3
#define TOK 49
#define MLPH 384
#define SCALE 0.17677669529663687f  // 1/sqrt(32)

typedef short bf16x8 __attribute__((ext_vector_type(8)));
typedef float f32x4 __attribute__((ext_vector_type(4)));

#define MFMA(a, b, c) __builtin_amdgcn_mfma_f32_16x16x32_bf16((a), (b), (c), 0, 0, 0)

__device__ __forceinline__ bf16x8 ldfrag(const __hip_bfloat16* p) {
    return *(const bf16x8*)p;
}
__device__ __forceinline__ unsigned short f2bf(float f) {
    __hip_bfloat16 h = __float2bfloat16(f);
    unsigned short u; __builtin_memcpy(&u, &h, 2); return u;
}
// packed 2x f32 -> bf16x2 in one instruction (RNE; low word = lo, high word = hi)
__device__ __forceinline__ unsigned int pk2(float lo, float hi) {
    unsigned int r;
    asm("v_cvt_pk_bf16_f32 %0, %1, %2" : "=v"(r) : "v"(lo), "v"(hi));
    return r;
}

// ws layout: bf16 weights [0,110592): qkvw 288x96 | projw 96x96 @27648 | fc1w 384x96 @36864 | fc2w 96x384 @73728
// then float btab[4 cat][3 h][64 q][64 k] at byte offset 221184 (196608 B)
__global__ __launch_bounds__(256) void prep(
    const float* __restrict__ qkvw, const float* __restrict__ projw,
    const float* __restrict__ fc1w, const float* __restrict__ fc2w,
    const float* __restrict__ relb,
    __hip_bfloat16* __restrict__ wbf, float* __restrict__ btab)
{
    int i = blockIdx.x * 256 + threadIdx.x;
    if (i < 27648)        wbf[i] = __float2bfloat16(qkvw[i]);
    else if (i < 36864)   wbf[i] = __float2bfloat16(projw[i - 27648]);
    else if (i < 73728)   wbf[i] = __float2bfloat16(fc1w[i - 36864]);
    else if (i < 110592)  wbf[i] = __float2bfloat16(fc2w[i - 73728]);
    else {
        int j = i - 110592;                 // [0, 49152)
        int cat = j / 12288;
        int r = j - cat * 12288;
        int h = r >> 12;
        int r2 = r & 4095;
        int q = r2 >> 6, k = r2 & 63;       // q outer, k inner (float4 along k)
        float v;
        if (k >= TOK) v = -10000.f;         // kill pad-k columns in softmax
        else if (q >= TOK) v = 0.f;         // pad-q rows: don't care
        else {
            int qi = q / WIN, qj = q - qi * WIN;
            int ki = k / WIN, kj = k - ki * WIN;
            int ridx = (qi - ki + 6) * 13 + (qj - kj + 6);
            v = relb[ridx * HEADS + h];
            int rqh = (cat & 2) ? (qi < 4 ? 1 : 2) : 0;
            int rqw = (cat & 1) ? (qj < 4 ? 1 : 2) : 0;
            int rkh = (cat & 2) ? (ki < 4 ? 1 : 2) : 0;
            int rkw = (cat & 1) ? (kj < 4 ? 1 : 2) : 0;
            if (rqh * 3 + rqw != rkh * 3 + rkw) v -= 100.f;
        }
        btab[j] = v;
    }
}

// LDS arena (40448 B; occupancy measured pinned at ~3 blocks/CU for any size
// 39-50 KB [r13/r16/r17], so LDS size is a free variable — use the
// conflict-friendly padded strides):
//   XL [64][104] bf16 @0      : Q (written by qkv) -> attn-out -> LN2'd res
//   Kf [64][104] bf16 @13312  : K (dead after attn)
//   Vt [96][72]  bf16 @26624  : V^T [d][tok] (dead after attn; ends 40448)
//   Hs [64][200] bf16 @13312  : MLP hidden chunk (overlays Kf+Vt; ends 38912)
//   part [64][2][2] f32 @38912: LN2 partials (dead-Vt tail; outside Hs)
// LN1 is fully register-resident (no XL staging, no B1/B2 barriers);
// P transpose fully in registers via __shfl (no Pw buffer). 8 barriers total.
#define OFF_KF 13312
#define OFF_VT 26624
#define OFF_PART 38912
#define ARENA_BYTES 40448

__global__ __launch_bounds__(256, 3) void swin_fused(
    const float* __restrict__ x,
    const float* __restrict__ n1w, const float* __restrict__ n1b,
    const __hip_bfloat16* __restrict__ wqkv, const float* __restrict__ qkvb,
    const float* __restrict__ btab,
    const __hip_bfloat16* __restrict__ wproj, const float* __restrict__ projb,
    const float* __restrict__ n2w, const float* __restrict__ n2b,
    const __hip_bfloat16* __restrict__ w1, const float* __restrict__ b1,
    const __hip_bfloat16* __restrict__ w2, const float* __restrict__ b2,
    float* __restrict__ out)
{
    __shared__ __align__(16) char arena[ARENA_BYTES];
    auto XL   = (__hip_bfloat16(*)[104])(arena);
    auto Kf   = (__hip_bfloat16(*)[104])(arena + OFF_KF);
    auto Vt   = (__hip_bfloat16(*)[72])(arena + OFF_VT);
    auto Hs   = (__hip_bfloat16(*)[200])(arena + OFF_KF);
    auto part = (float(*)[2][2])(arena + OFF_PART);

    const int blk = blockIdx.x;
    const int b = blk >> 6, win = blk & 63;
    const int wi = win >> 3, wj = win & 7;
    const int cat = ((wi == 7) << 1) | (wj == 7);
    const int tid = threadIdx.x;
    const int lane = tid & 63, w = tid >> 6;
    const int lr = lane & 15, g = lane >> 4;
    const int k0 = g * 8;
    const size_t bbase = (size_t)b * (HH * HH * CH);

    // ---- Phase 0: LN1 fully in registers -> Bx MFMA fragments (no LDS, no barrier).
    //      Lane (lr,g) owns tokens tt*16+lr, channels {32ks+8g .. +7}; the 4 g-lanes
    //      of a token cover all 96 ch -> stats via shfl_xor(16/32) g-reduce. ----
    bf16x8 Bx[4][3];
    {
        // LN1 weight/bias fragments for this lane's channel slots (same for all tt)
        f32x4 w1v[3][2], b1v[3][2];
        #pragma unroll
        for (int ks = 0; ks < 3; ++ks) {
            w1v[ks][0] = *(const f32x4*)(n1w + ks * 32 + 8 * g);
            w1v[ks][1] = *(const f32x4*)(n1w + ks * 32 + 8 * g + 4);
            b1v[ks][0] = *(const f32x4*)(n1b + ks * 32 + 8 * g);
            b1v[ks][1] = *(const f32x4*)(n1b + ks * 32 + 8 * g + 4);
        }
        #pragma unroll
        for (int tt = 0; tt < 4; ++tt) {
            int tokr = tt * 16 + lr;
            float v[24];
            if (tokr < TOK) {
                int ti = tokr / WIN, tj = tokr - (tokr / WIN) * WIN;
                int ph = wi * WIN + ti + SHIFT; if (ph >= HH) ph -= HH;
                int pw = wj * WIN + tj + SHIFT; if (pw >= HH) pw -= HH;
                const float* xr = x + bbase + (size_t)(ph * HH + pw) * CH;
                #pragma unroll
                for (int ks = 0; ks < 3; ++ks) {
                    f32x4 f0 = *(const f32x4*)(xr + ks * 32 + 8 * g);
                    f32x4 f1 = *(const f32x4*)(xr + ks * 32 + 8 * g + 4);
                    #pragma unroll
                    for (int j = 0; j < 4; ++j) { v[ks*8 + j] = f0[j]; v[ks*8 + 4 + j] = f1[j]; }
                }
            } else {
                #pragma unroll
                for (int i = 0; i < 24; ++i) v[i] = 0.f;
            }
            float s = 0.f, s2 = 0.f;
            #pragma unroll
            for (int i = 0; i < 24; ++i) { s += v[i]; s2 += v[i] * v[i]; }
            s  += __shfl_xor(s, 16);  s  += __shfl_xor(s, 32);
            s2 += __shfl_xor(s2, 16); s2 += __shfl_xor(s2, 32);
            float mu = s * (1.f / CH);
            float rstd = rsqrtf(s2 * (1.f / CH) - mu * mu + 1e-5f);
            if (tokr < TOK) {
                #pragma unroll
                for (int ks = 0; ks < 3; ++ks) {
                    uint4 t;
                    t.x = pk2((v[ks*8+0] - mu) * rstd * w1v[ks][0][0] + b1v[ks][0][0],
                              (v[ks*8+1] - mu) * rstd * w1v[ks][0][1] + b1v[ks][0][1]);
                    t.y = pk2((v[ks*8+2] - mu) * rstd * w1v[ks][0][2] + b1v[ks][0][2],
                              (v[ks*8+3] - mu) * rstd * w1v[ks][0][3] + b1v[ks][0][3]);
                    t.z = pk2((v[ks*8+4] - mu) * rstd * w1v[ks][1][0] + b1v[ks][1][0],
                              (v[ks*8+5] - mu) * rstd * w1v[ks][1][1] + b1v[ks][1][1]);
                    t.w = pk2((v[ks*8+6] - mu) * rstd * w1v[ks][1][2] + b1v[ks][1][2],
                              (v[ks*8+7] - mu) * rstd * w1v[ks][1][3] + b1v[ks][1][3]);
                    __builtin_memcpy(&Bx[tt][ks], &t, 16);
                }
            } else {
                #pragma unroll
                for (int ks = 0; ks < 3; ++ks) {
                    uint4 t; t.x = t.y = t.z = t.w = 0u;
                    __builtin_memcpy(&Bx[tt][ks], &t, 16);
                }
            }
        }
    }

    // ---- Phase 1: qkv GEMM, D[channel][token]; Q -> XL (XL has no prior content) ----
    {
        #pragma unroll
        for (int nn = 0; nn < 5; ++nn) {
            int n = w + 4 * nn;
            if (n < 18) {
                const __hip_bfloat16* wp = wqkv + (n * 16 + lr) * CH + k0;
                bf16x8 Af[3];
                #pragma unroll
                for (int ks = 0; ks < 3; ++ks) Af[ks] = ldfrag(wp + ks * 32);
                f32x4 acc[4];
                #pragma unroll
                for (int tt = 0; tt < 4; ++tt) acc[tt] = (f32x4){0.f, 0.f, 0.f, 0.f};
                #pragma unroll
                for (int ks = 0; ks < 3; ++ks)
                    #pragma unroll
                    for (int tt = 0; tt < 4; ++tt)
                        acc[tt] = MFMA(Af[ks], Bx[tt][ks], acc[tt]);
                f32x4 b4 = *(const f32x4*)(qkvb + n * 16 + 4 * g);
                #pragma unroll
                for (int tt = 0; tt < 4; ++tt) {
                    int tokr = tt * 16 + lr;
                    if (n < 6) {
                        uint2 t;
                        t.x = pk2((acc[tt][0] + b4[0]) * SCALE, (acc[tt][1] + b4[1]) * SCALE);
                        t.y = pk2((acc[tt][2] + b4[2]) * SCALE, (acc[tt][3] + b4[3]) * SCALE);
                        *(uint2*)&XL[tokr][n * 16 + 4 * g] = t;   // Q -> XL
                    } else if (n < 12) {
                        uint2 t;
                        t.x = pk2(acc[tt][0] + b4[0], acc[tt][1] + b4[1]);
                        t.y = pk2(acc[tt][2] + b4[2], acc[tt][3] + b4[3]);
                        *(uint2*)&Kf[tokr][(n - 6) * 16 + 4 * g] = t;
                    } else {
                        #pragma unroll
                        for (int j = 0; j < 4; ++j)
                            Vt[(n - 12) * 16 + 4 * g + j][tokr] =
                                __float2bfloat16(acc[tt][j] + b4[j]);
                    }
                }
            }
        }
    }
    __syncthreads();   // B3: Q/K/V visible

    // ---- Phase 2: attention units, wave w = q-tile w, all heads; P transposed in regs ----
    for (int u = w; u < 12; u += 4) {
        int h = u >> 2, qt = u & 3;
        bf16x8 qfrag = ldfrag(&XL[qt * 16 + lr][h * 32 + k0]);   // Q from XL
        f32x4 s[4];
        #pragma unroll
        for (int kt = 0; kt < 4; ++kt) {
            f32x4 z = {0.f, 0.f, 0.f, 0.f};
            s[kt] = MFMA(ldfrag(&Kf[kt * 16 + lr][h * 32 + k0]), qfrag, z);
        }
        const float* bt = btab + (((cat * HEADS + h) << 12) | ((qt * 16 + lr) << 6));
        #pragma unroll
        for (int kt = 0; kt < 4; ++kt)
            s[kt] += *(const f32x4*)(bt + kt * 16 + 4 * g);
        float m = -1e30f;
        #pragma unroll
        for (int kt = 0; kt < 4; ++kt)
            #pragma unroll
            for (int j = 0; j < 4; ++j) m = fmaxf(m, s[kt][j]);
        m = fmaxf(m, __shfl_xor(m, 16));
        m = fmaxf(m, __shfl_xor(m, 32));
        float e[4][4]; float sum = 0.f;
        #pragma unroll
        for (int kt = 0; kt < 4; ++kt)
            #pragma unroll
            for (int j = 0; j < 4; ++j) { e[kt][j] = __expf(s[kt][j] - m); sum += e[kt][j]; }
        sum += __shfl_xor(sum, 16);
        sum += __shfl_xor(sum, 32);
        float inv = 1.f / sum;
        // pack P pairs: pu[2kt+half] holds P[k=16kt+4g+2*half .. +1][q=lr], bf16x2
        unsigned pu[8];
        #pragma unroll
        for (int kt = 0; kt < 4; ++kt) {
            pu[2*kt]   = pk2(e[kt][0] * inv, e[kt][1] * inv);
            pu[2*kt+1] = pk2(e[kt][2] * inv, e[kt][3] * inv);
        }
        // in-register transpose: lane (lr,g) gathers P^T[q=lr][k=32ks+8g+0..7].
        // pair k=32ks+8g+2t lives in lane (2(g&1)+(t>=2))*16+lr, reg pu[4ks+2(g>>1)+(t&1)].
        const int s_lo = ((g & 1) << 5) + lr;
        const int s_hi = s_lo + 16;
        const bool ghi = (g & 2) != 0;
        uint4 pbv[2];
        #pragma unroll
        for (int ks = 0; ks < 2; ++ks) {
            unsigned vv[4];
            #pragma unroll
            for (int t = 0; t < 4; ++t) {
                int src = (t < 2) ? s_lo : s_hi;
                unsigned a = __shfl(pu[4*ks + (t & 1)], src);
                unsigned bsel = __shfl(pu[4*ks + 2 + (t & 1)], src);
                vv[t] = ghi ? bsel : a;
            }
            pbv[ks].x = vv[0]; pbv[ks].y = vv[1]; pbv[ks].z = vv[2]; pbv[ks].w = vv[3];
        }
        // PV: O[q][d] = mfma(A = P^T rows (regs), B = Vt rows)
        #pragma unroll
        for (int dt = 0; dt < 2; ++dt) {
            f32x4 o = {0.f, 0.f, 0.f, 0.f};
            #pragma unroll
            for (int ks = 0; ks < 2; ++ks) {
                bf16x8 pa;
                __builtin_memcpy(&pa, &pbv[ks], 16);
                bf16x8 vb = ldfrag(&Vt[h * 32 + dt * 16 + lr][ks * 32 + k0]);
                o = MFMA(pa, vb, o);
            }
            #pragma unroll
            for (int j = 0; j < 4; ++j)
                XL[qt * 16 + g * 4 + j][h * 32 + dt * 16 + lr] = __float2bfloat16(o[j]);
        }
    }
    __syncthreads();   // B4: attn-out complete in XL

    // ---- Phase 3: proj + residual, (mh,nh) split matching fc2; res stays in REGISTERS ----
    const int mh = w & 1, nh = w >> 1;
    size_t rowoff[2];
    int tokv[2];
    #pragma unroll
    for (int mi = 0; mi < 2; ++mi) {
        int tokr = mh * 32 + mi * 16 + lr;
        tokv[mi] = tokr;
        int ti = tokr / WIN, tj = tokr - (tokr / WIN) * WIN;
        int ph = wi * WIN + ti + SHIFT; if (ph >= HH) ph -= HH;
        int pw = wj * WIN + tj + SHIFT; if (pw >= HH) pw -= HH;
        rowoff[mi] = bbase + (size_t)(ph * HH + pw) * CH;
    }
    f32x4 res[3][2];
    {
        bf16x8 Bx2[2][3];
        #pragma unroll
        for (int mi = 0; mi < 2; ++mi)
            #pragma unroll
            for (int ks = 0; ks < 3; ++ks)
                Bx2[mi][ks] = ldfrag(&XL[(mh * 2 + mi) * 16 + lr][ks * 32 + k0]);
        #pragma unroll
        for (int nt = 0; nt < 3; ++nt) {
            int ch0 = nh * 48 + nt * 16;
            const __hip_bfloat16* wp = wproj + (ch0 + lr) * CH + k0;
            bf16x8 Af[3];
            #pragma unroll
            for (int ks = 0; ks < 3; ++ks) Af[ks] = ldfrag(wp + ks * 32);
            f32x4 acc[2];
            acc[0] = (f32x4){0.f, 0.f, 0.f, 0.f};
            acc[1] = (f32x4){0.f, 0.f, 0.f, 0.f};
            #pragma unroll
            for (int ks = 0; ks < 3; ++ks) {
                acc[0] = MFMA(Af[ks], Bx2[0][ks], acc[0]);
                acc[1] = MFMA(Af[ks], Bx2[1][ks], acc[1]);
            }
            f32x4 pb4 = *(const f32x4*)(projb + ch0 + 4 * g);
            #pragma unroll
            for (int mi = 0; mi < 2; ++mi) {
                f32x4 x4 = *(const f32x4*)(x + rowoff[mi] + ch0 + 4 * g);
                res[nt][mi] = acc[mi] + pb4 + x4;
            }
        }
    }

    // ---- Phase 4: LN2 stats (register res -> shuffle over g -> part LDS -> mu/rstd) ----
    {
        float s[2] = {0.f, 0.f}, s2[2] = {0.f, 0.f};
        #pragma unroll
        for (int mi = 0; mi < 2; ++mi)
            #pragma unroll
            for (int nt = 0; nt < 3; ++nt)
                #pragma unroll
                for (int j = 0; j < 4; ++j) {
                    float v = res[nt][mi][j];
                    s[mi] += v; s2[mi] += v * v;
                }
        #pragma unroll
        for (int mi = 0; mi < 2; ++mi) {
            s[mi]  += __shfl_xor(s[mi], 16);  s[mi]  += __shfl_xor(s[mi], 32);
            s2[mi] += __shfl_xor(s2[mi], 16); s2[mi] += __shfl_xor(s2[mi], 32);
            if (g == 0) {
                part[tokv[mi]][nh][0] = s[mi];
                part[tokv[mi]][nh][1] = s2[mi];
            }
        }
    }
    __syncthreads();   // B5: partials complete (also: all Bx2 reads of XL done)
    float mu[2], rstd[2];
    #pragma unroll
    for (int mi = 0; mi < 2; ++mi) {
        float ts  = part[tokv[mi]][0][0] + part[tokv[mi]][1][0];
        float ts2 = part[tokv[mi]][0][1] + part[tokv[mi]][1][1];
        mu[mi] = ts * (1.f / CH);
        rstd[mi] = rsqrtf(ts2 * (1.f / CH) - mu[mi] * mu[mi] + 1e-5f);
    }
    // write LN2'd res into XL (rows 32mh.., ch 48nh.. — disjoint across waves)
    #pragma unroll
    for (int nt = 0; nt < 3; ++nt) {
        int ch0 = nh * 48 + nt * 16 + 4 * g;
        f32x4 w4 = *(const f32x4*)(n2w + ch0);
        f32x4 b4 = *(const f32x4*)(n2b + ch0);
        #pragma unroll
        for (int mi = 0; mi < 2; ++mi) {
            uint2 t;
            t.x = pk2((res[nt][mi][0] - mu[mi]) * rstd[mi] * w4[0] + b4[0],
                      (res[nt][mi][1] - mu[mi]) * rstd[mi] * w4[1] + b4[1]);
            t.y = pk2((res[nt][mi][2] - mu[mi]) * rstd[mi] * w4[2] + b4[2],
                      (res[nt][mi][3] - mu[mi]) * rstd[mi] * w4[3] + b4[3]);
            *(uint2*)&XL[tokv[mi]][ch0] = t;
        }
    }
    __syncthreads();   // B6: XL = LN2'd res; part consumed; Kf/Vt dead -> Hs may overlay

    // ---- Phase 5: MLP, 2 k-chunks of 192 ----
    f32x4 acc2[3][2];
    #pragma unroll
    for (int nt = 0; nt < 3; ++nt)
        #pragma unroll
        for (int mi = 0; mi < 2; ++mi) acc2[nt][mi] = (f32x4){0.f, 0.f, 0.f, 0.f};

    #pragma unroll
    for (int c = 0; c < 2; ++c) {
        bf16x8 Bm[4][3];
        #pragma unroll
        for (int tt = 0; tt < 4; ++tt)
            #pragma unroll
            for (int ks = 0; ks < 3; ++ks)
                Bm[tt][ks] = ldfrag(&XL[tt * 16 + lr][ks * 32 + k0]);

        #pragma unroll
        for (int nn = 0; nn < 3; ++nn) {
            int nl = w + 4 * nn;
            int ncol = c * 192 + nl * 16;
            const __hip_bfloat16* wp = w1 + (ncol + lr) * CH + k0;
            bf16x8 Af[3];
            #pragma unroll
            for (int ks = 0; ks < 3; ++ks) Af[ks] = ldfrag(wp + ks * 32);
            f32x4 acc[4];
            #pragma unroll
            for (int tt = 0; tt < 4; ++tt) acc[tt] = (f32x4){0.f, 0.f, 0.f, 0.f};
            #pragma unroll
            for (int ks = 0; ks < 3; ++ks)
                #pragma unroll
                for (int tt = 0; tt < 4; ++tt)
                    acc[tt] = MFMA(Af[ks], Bm[tt][ks], acc[tt]);
            f32x4 b4 = *(const f32x4*)(b1 + ncol + 4 * g);
            #pragma unroll
            for (int tt = 0; tt < 4; ++tt) {
                float gv[4];
                #pragma unroll
                for (int j = 0; j < 4; ++j) {
                    float v = acc[tt][j] + b4[j];
                    gv[j] = v * __builtin_amdgcn_rcpf(1.f + __expf(-1.702f * v));
                }
                uint2 t;
                t.x = pk2(gv[0], gv[1]);
                t.y = pk2(gv[2], gv[3]);
                *(uint2*)&Hs[tt * 16 + lr][nl * 16 + 4 * g] = t;
            }
        }
        __syncthreads();   // fc1 chunk visible

        #pragma unroll
        for (int k = 0; k < 6; ++k) {
            bf16x8 h0 = ldfrag(&Hs[mh * 32 + lr][k * 32 + k0]);
            bf16x8 h1 = ldfrag(&Hs[mh * 32 + 16 + lr][k * 32 + k0]);
            #pragma unroll
            for (int nt = 0; nt < 3; ++nt) {
                bf16x8 Af = ldfrag(w2 + (nh * 48 + nt * 16 + lr) * MLPH + c * 192 + k * 32 + k0);
                acc2[nt][0] = MFMA(Af, h0, acc2[nt][0]);
                acc2[nt][1] = MFMA(Af, h1, acc2[nt][1]);
            }
        }
        __syncthreads();   // fc2 reads done before next chunk overwrites Hs
    }

    // ---- Phase 6: single out write = res(regs) + mlp + bias ----
    #pragma unroll
    for (int nt = 0; nt < 3; ++nt) {
        f32x4 b4 = *(const f32x4*)(b2 + nh * 48 + nt * 16 + 4 * g);
        #pragma unroll
        for (int mi = 0; mi < 2; ++mi) {
            if (tokv[mi] < TOK) {
                size_t gi = rowoff[mi] + nh * 48 + nt * 16 + 4 * g;
                *(f32x4*)(out + gi) = res[nt][mi] + acc2[nt][mi] + b4;
            }
        }
    }
}

extern "C" void kernel_launch(void* const* d_in, const int* in_sizes, int n_in,
                              void* d_out, int out_size, void* d_ws, size_t ws_size,
                              hipStream_t stream) {
    const float* x     = (const float*)d_in[0];
    const float* n1w   = (const float*)d_in[1];
    const float* n1b   = (const float*)d_in[2];
    const float* qkvw  = (const float*)d_in[3];
    const float* qkvb  = (const float*)d_in[4];
    const float* relb  = (const float*)d_in[5];
    const float* projw = (const float*)d_in[6];
    const float* projb = (const float*)d_in[7];
    const float* n2w   = (const float*)d_in[8];
    const float* n2b   = (const float*)d_in[9];
    const float* fc1w  = (const float*)d_in[10];
    const float* fc1b  = (const float*)d_in[11];
    const float* fc2w  = (const float*)d_in[12];
    const float* fc2b  = (const float*)d_in[13];
    float* out = (float*)d_out;

    __hip_bfloat16* wbf = (__hip_bfloat16*)d_ws;
    float* btab = (float*)((char*)d_ws + 221184);
    const __hip_bfloat16* wqkv  = wbf;
    const __hip_bfloat16* wproj = wbf + 27648;
    const __hip_bfloat16* wfc1  = wbf + 36864;
    const __hip_bfloat16* wfc2  = wbf + 73728;

    prep<<<624, 256, 0, stream>>>(qkvw, projw, fc1w, fc2w, relb, wbf, btab);
    swin_fused<<<BATCH * 64, 256, 0, stream>>>(
        x, n1w, n1b, wqkv, qkvb, btab, wproj, projb,
        n2w, n2b, wfc1, fc1b, wfc2, fc2b, out);
}

// Round 20
// 184.595 us; speedup vs baseline: 1.1601x; 1.1601x over previous
//
#include <hip/hip_runtime.h>
#include <hip/hip_bf16.h>
#include <math.h>

#define BATCH 64
#define HH 56
#define CH 96
#define HEADS 3
#define WIN 7
#define SHIFT 3
#define TOK 49
#define MLPH 384
#define SCALE 0.17677669529663687f  // 1/sqrt(32)

typedef short bf16x8 __attribute__((ext_vector_type(8)));
typedef float f32x4 __attribute__((ext_vector_type(4)));

#define MFMA(a, b, c) __builtin_amdgcn_mfma_f32_16x16x32_bf16((a), (b), (c), 0, 0, 0)

__device__ __forceinline__ bf16x8 ldfrag(const __hip_bfloat16* p) {
    return *(const bf16x8*)p;
}
__device__ __forceinline__ unsigned short f2bf(float f) {
    __hip_bfloat16 h = __float2bfloat16(f);
    unsigned short u; __builtin_memcpy(&u, &h, 2); return u;
}
// packed 2x f32 -> bf16x2 in one instruction (RNE; low word = lo, high word = hi)
__device__ __forceinline__ unsigned int pk2(float lo, float hi) {
    unsigned int r;
    asm("v_cvt_pk_bf16_f32 %0, %1, %2" : "=v"(r) : "v"(lo), "v"(hi));
    return r;
}

// ws layout: bf16 weights [0,110592): qkvw 288x96 | projw 96x96 @27648 | fc1w 384x96 @36864 | fc2w 96x384 @73728
// then float btab[4 cat][3 h][64 q][64 k] at byte offset 221184 (196608 B)
__global__ __launch_bounds__(256) void prep(
    const float* __restrict__ qkvw, const float* __restrict__ projw,
    const float* __restrict__ fc1w, const float* __restrict__ fc2w,
    const float* __restrict__ relb,
    __hip_bfloat16* __restrict__ wbf, float* __restrict__ btab)
{
    int i = blockIdx.x * 256 + threadIdx.x;
    if (i < 27648)        wbf[i] = __float2bfloat16(qkvw[i]);
    else if (i < 36864)   wbf[i] = __float2bfloat16(projw[i - 27648]);
    else if (i < 73728)   wbf[i] = __float2bfloat16(fc1w[i - 36864]);
    else if (i < 110592)  wbf[i] = __float2bfloat16(fc2w[i - 73728]);
    else {
        int j = i - 110592;                 // [0, 49152)
        int cat = j / 12288;
        int r = j - cat * 12288;
        int h = r >> 12;
        int r2 = r & 4095;
        int q = r2 >> 6, k = r2 & 63;       // q outer, k inner (float4 along k)
        float v;
        if (k >= TOK) v = -10000.f;         // kill pad-k columns in softmax
        else if (q >= TOK) v = 0.f;         // pad-q rows: don't care
        else {
            int qi = q / WIN, qj = q - qi * WIN;
            int ki = k / WIN, kj = k - ki * WIN;
            int ridx = (qi - ki + 6) * 13 + (qj - kj + 6);
            v = relb[ridx * HEADS + h];
            int rqh = (cat & 2) ? (qi < 4 ? 1 : 2) : 0;
            int rqw = (cat & 1) ? (qj < 4 ? 1 : 2) : 0;
            int rkh = (cat & 2) ? (ki < 4 ? 1 : 2) : 0;
            int rkw = (cat & 1) ? (kj < 4 ? 1 : 2) : 0;
            if (rqh * 3 + rqw != rkh * 3 + rkw) v -= 100.f;
        }
        btab[j] = v;
    }
}

// LDS arena (40448 B) — r16 layout (best measured base):
//   XL [64][104] bf16 @0      : LN1'd x -> Q (written back) -> attn-out -> LN2'd res
//   Kf [64][104] bf16 @13312  : K (dead after attn)
//   Vt [96][72]  bf16 @26624  : V^T [d][tok] (dead after attn; ends 40448)
//   Hs [64][200] bf16 @13312  : MLP hidden chunk (overlays Kf+Vt; ends 38912)
//   part [64][2][2] f32 @38912: LN2 partials (dead-Vt tail; outside Hs)
// P transpose fully in registers via __shfl (no Pw buffer).
// r20: cross-barrier prefetch — each post-barrier phase's first global loads
// (weights/btab/x) are issued BEFORE the preceding __syncthreads, so their
// latency overlaps the barrier's vmcnt(0) drain (when waves idle anyway).
#define OFF_KF 13312
#define OFF_VT 26624
#define OFF_PART 38912
#define ARENA_BYTES 40448

__global__ __launch_bounds__(256, 3) void swin_fused(
    const float* __restrict__ x,
    const float* __restrict__ n1w, const float* __restrict__ n1b,
    const __hip_bfloat16* __restrict__ wqkv, const float* __restrict__ qkvb,
    const float* __restrict__ btab,
    const __hip_bfloat16* __restrict__ wproj, const float* __restrict__ projb,
    const float* __restrict__ n2w, const float* __restrict__ n2b,
    const __hip_bfloat16* __restrict__ w1, const float* __restrict__ b1,
    const __hip_bfloat16* __restrict__ w2, const float* __restrict__ b2,
    float* __restrict__ out)
{
    __shared__ __align__(16) char arena[ARENA_BYTES];
    auto XL   = (__hip_bfloat16(*)[104])(arena);
    auto Kf   = (__hip_bfloat16(*)[104])(arena + OFF_KF);
    auto Vt   = (__hip_bfloat16(*)[72])(arena + OFF_VT);
    auto Hs   = (__hip_bfloat16(*)[200])(arena + OFF_KF);
    auto part = (float(*)[2][2])(arena + OFF_PART);

    const int blk = blockIdx.x;
    const int b = blk >> 6, win = blk & 63;
    const int wi = win >> 3, wj = win & 7;
    const int cat = ((wi == 7) << 1) | (wj == 7);
    const int tid = threadIdx.x;
    const int lane = tid & 63, w = tid >> 6;
    const int lr = lane & 15, g = lane >> 4;
    const int k0 = g * 8;
    const size_t bbase = (size_t)b * (HH * HH * CH);
    const int mh = w & 1, nh = w >> 1;

    // per-wave token/row bookkeeping for proj/fc2/epilogue (pure arithmetic)
    size_t rowoff[2];
    int tokv[2];
    #pragma unroll
    for (int mi = 0; mi < 2; ++mi) {
        int tokr = mh * 32 + mi * 16 + lr;
        tokv[mi] = tokr;
        int ti = tokr / WIN, tj = tokr - (tokr / WIN) * WIN;
        int ph = wi * WIN + ti + SHIFT; if (ph >= HH) ph -= HH;
        int pw = wj * WIN + tj + SHIFT; if (pw >= HH) pw -= HH;
        rowoff[mi] = bbase + (size_t)(ph * HH + pw) * CH;
    }

    // ---- Phase 0: LN1 + shifted-window gather (4 threads/row); zero pad rows ----
    {
        int r = tid >> 2, p = tid & 3;
        if (r < TOK) {
            int ti = r / WIN, tj = r - (r / WIN) * WIN;
            int ph = wi * WIN + ti + SHIFT; if (ph >= HH) ph -= HH;
            int pw = wj * WIN + tj + SHIFT; if (pw >= HH) pw -= HH;
            const float4* xr = (const float4*)(x + bbase + (size_t)(ph * HH + pw) * CH + p * 24);
            float v[24]; float s = 0.f, s2 = 0.f;
            #pragma unroll
            for (int i = 0; i < 6; ++i) {
                float4 f = xr[i];
                v[4*i] = f.x; v[4*i+1] = f.y; v[4*i+2] = f.z; v[4*i+3] = f.w;
            }
            #pragma unroll
            for (int i = 0; i < 24; ++i) { s += v[i]; s2 += v[i] * v[i]; }
            s  += __shfl_xor(s, 1);  s  += __shfl_xor(s, 2);
            s2 += __shfl_xor(s2, 1); s2 += __shfl_xor(s2, 2);
            float mu = s * (1.f / CH);
            float rstd = rsqrtf(s2 * (1.f / CH) - mu * mu + 1e-5f);
            #pragma unroll
            for (int i = 0; i < 6; ++i) {
                const float* wp4 = n1w + p * 24 + 4 * i;
                const float* bp4 = n1b + p * 24 + 4 * i;
                uint2 t;
                t.x = pk2((v[4*i]   - mu) * rstd * wp4[0] + bp4[0],
                          (v[4*i+1] - mu) * rstd * wp4[1] + bp4[1]);
                t.y = pk2((v[4*i+2] - mu) * rstd * wp4[2] + bp4[2],
                          (v[4*i+3] - mu) * rstd * wp4[3] + bp4[3]);
                *(uint2*)&XL[r][p * 24 + 4 * i] = t;
            }
        } else {
            uint2 z; z.x = 0u; z.y = 0u;
            #pragma unroll
            for (int i = 0; i < 6; ++i) *(uint2*)&XL[r][p * 24 + 4 * i] = z;
        }
    }
    // prefetch qkv weights for first N-tile (n = w) across B1/B2
    bf16x8 pfQ[3];
    {
        const __hip_bfloat16* wp = wqkv + (w * 16 + lr) * CH + k0;
        #pragma unroll
        for (int ks = 0; ks < 3; ++ks) pfQ[ks] = ldfrag(wp + ks * 32);
    }
    __syncthreads();   // B1: LN1 complete

    // ---- Phase 1: qkv GEMM, D[channel][token]; Q written back into XL ----
    {
        bf16x8 Bx[4][3];
        #pragma unroll
        for (int tt = 0; tt < 4; ++tt)
            #pragma unroll
            for (int ks = 0; ks < 3; ++ks)
                Bx[tt][ks] = ldfrag(&XL[tt * 16 + lr][ks * 32 + k0]);
        __syncthreads();   // B2: all waves hold LN1 frags in regs; XL may be overwritten (Q)

        #pragma unroll
        for (int nn = 0; nn < 5; ++nn) {
            int n = w + 4 * nn;
            if (n < 18) {
                bf16x8 Af[3];
                if (nn == 0) {
                    #pragma unroll
                    for (int ks = 0; ks < 3; ++ks) Af[ks] = pfQ[ks];
                } else {
                    const __hip_bfloat16* wp = wqkv + (n * 16 + lr) * CH + k0;
                    #pragma unroll
                    for (int ks = 0; ks < 3; ++ks) Af[ks] = ldfrag(wp + ks * 32);
                }
                f32x4 acc[4];
                #pragma unroll
                for (int tt = 0; tt < 4; ++tt) acc[tt] = (f32x4){0.f, 0.f, 0.f, 0.f};
                #pragma unroll
                for (int ks = 0; ks < 3; ++ks)
                    #pragma unroll
                    for (int tt = 0; tt < 4; ++tt)
                        acc[tt] = MFMA(Af[ks], Bx[tt][ks], acc[tt]);
                f32x4 b4 = *(const f32x4*)(qkvb + n * 16 + 4 * g);
                #pragma unroll
                for (int tt = 0; tt < 4; ++tt) {
                    int tokr = tt * 16 + lr;
                    if (n < 6) {
                        uint2 t;
                        t.x = pk2((acc[tt][0] + b4[0]) * SCALE, (acc[tt][1] + b4[1]) * SCALE);
                        t.y = pk2((acc[tt][2] + b4[2]) * SCALE, (acc[tt][3] + b4[3]) * SCALE);
                        *(uint2*)&XL[tokr][n * 16 + 4 * g] = t;   // Q -> XL
                    } else if (n < 12) {
                        uint2 t;
                        t.x = pk2(acc[tt][0] + b4[0], acc[tt][1] + b4[1]);
                        t.y = pk2(acc[tt][2] + b4[2], acc[tt][3] + b4[3]);
                        *(uint2*)&Kf[tokr][(n - 6) * 16 + 4 * g] = t;
                    } else {
                        #pragma unroll
                        for (int j = 0; j < 4; ++j)
                            Vt[(n - 12) * 16 + 4 * g + j][tokr] =
                                __float2bfloat16(acc[tt][j] + b4[j]);
                    }
                }
            }
        }
    }
    // prefetch btab for first attn unit (u = w -> h=0, qt=w) across B3
    f32x4 pfB[4];
    {
        const float* bt0 = btab + (((cat * HEADS + 0) << 12) | ((w * 16 + lr) << 6));
        #pragma unroll
        for (int kt = 0; kt < 4; ++kt) pfB[kt] = *(const f32x4*)(bt0 + kt * 16 + 4 * g);
    }
    __syncthreads();   // B3: Q/K/V visible

    // ---- Phase 2: attention units (3 per wave: u = w, w+4, w+8); P transposed in regs ----
    #pragma unroll
    for (int it = 0; it < 3; ++it) {
        int u = w + 4 * it;
        int h = u >> 2, qt = u & 3;
        bf16x8 qfrag = ldfrag(&XL[qt * 16 + lr][h * 32 + k0]);   // Q from XL
        f32x4 s[4];
        #pragma unroll
        for (int kt = 0; kt < 4; ++kt) {
            f32x4 z = {0.f, 0.f, 0.f, 0.f};
            s[kt] = MFMA(ldfrag(&Kf[kt * 16 + lr][h * 32 + k0]), qfrag, z);
        }
        if (it == 0) {
            #pragma unroll
            for (int kt = 0; kt < 4; ++kt) s[kt] += pfB[kt];
        } else {
            const float* bt = btab + (((cat * HEADS + h) << 12) | ((qt * 16 + lr) << 6));
            #pragma unroll
            for (int kt = 0; kt < 4; ++kt)
                s[kt] += *(const f32x4*)(bt + kt * 16 + 4 * g);
        }
        float m = -1e30f;
        #pragma unroll
        for (int kt = 0; kt < 4; ++kt)
            #pragma unroll
            for (int j = 0; j < 4; ++j) m = fmaxf(m, s[kt][j]);
        m = fmaxf(m, __shfl_xor(m, 16));
        m = fmaxf(m, __shfl_xor(m, 32));
        float e[4][4]; float sum = 0.f;
        #pragma unroll
        for (int kt = 0; kt < 4; ++kt)
            #pragma unroll
            for (int j = 0; j < 4; ++j) { e[kt][j] = __expf(s[kt][j] - m); sum += e[kt][j]; }
        sum += __shfl_xor(sum, 16);
        sum += __shfl_xor(sum, 32);
        float inv = 1.f / sum;
        // pack P pairs: pu[2kt+half] holds P[k=16kt+4g+2*half .. +1][q=lr], bf16x2
        unsigned pu[8];
        #pragma unroll
        for (int kt = 0; kt < 4; ++kt) {
            pu[2*kt]   = pk2(e[kt][0] * inv, e[kt][1] * inv);
            pu[2*kt+1] = pk2(e[kt][2] * inv, e[kt][3] * inv);
        }
        // in-register transpose: lane (lr,g) gathers P^T[q=lr][k=32ks+8g+0..7].
        const int s_lo = ((g & 1) << 5) + lr;
        const int s_hi = s_lo + 16;
        const bool ghi = (g & 2) != 0;
        uint4 pbv[2];
        #pragma unroll
        for (int ks = 0; ks < 2; ++ks) {
            unsigned vv[4];
            #pragma unroll
            for (int t = 0; t < 4; ++t) {
                int src = (t < 2) ? s_lo : s_hi;
                unsigned a = __shfl(pu[4*ks + (t & 1)], src);
                unsigned bsel = __shfl(pu[4*ks + 2 + (t & 1)], src);
                vv[t] = ghi ? bsel : a;
            }
            pbv[ks].x = vv[0]; pbv[ks].y = vv[1]; pbv[ks].z = vv[2]; pbv[ks].w = vv[3];
        }
        // PV: O[q][d] = mfma(A = P^T rows (regs), B = Vt rows)
        #pragma unroll
        for (int dt = 0; dt < 2; ++dt) {
            f32x4 o = {0.f, 0.f, 0.f, 0.f};
            #pragma unroll
            for (int ks = 0; ks < 2; ++ks) {
                bf16x8 pa;
                __builtin_memcpy(&pa, &pbv[ks], 16);
                bf16x8 vb = ldfrag(&Vt[h * 32 + dt * 16 + lr][ks * 32 + k0]);
                o = MFMA(pa, vb, o);
            }
            #pragma unroll
            for (int j = 0; j < 4; ++j)
                XL[qt * 16 + g * 4 + j][h * 32 + dt * 16 + lr] = __float2bfloat16(o[j]);
        }
    }
    // prefetch proj weights (nt=0) + residual x (nt=0) across B4
    bf16x8 pfP[3];
    f32x4 pfX[2];
    {
        const __hip_bfloat16* wp = wproj + (nh * 48 + lr) * CH + k0;
        #pragma unroll
        for (int ks = 0; ks < 3; ++ks) pfP[ks] = ldfrag(wp + ks * 32);
        #pragma unroll
        for (int mi = 0; mi < 2; ++mi)
            pfX[mi] = *(const f32x4*)(x + rowoff[mi] + nh * 48 + 4 * g);
    }
    __syncthreads();   // B4: attn-out complete in XL

    // ---- Phase 3: proj + residual, (mh,nh) split matching fc2; res stays in REGISTERS ----
    f32x4 res[3][2];
    {
        bf16x8 Bx2[2][3];
        #pragma unroll
        for (int mi = 0; mi < 2; ++mi)
            #pragma unroll
            for (int ks = 0; ks < 3; ++ks)
                Bx2[mi][ks] = ldfrag(&XL[(mh * 2 + mi) * 16 + lr][ks * 32 + k0]);
        #pragma unroll
        for (int nt = 0; nt < 3; ++nt) {
            int ch0 = nh * 48 + nt * 16;
            bf16x8 Af[3];
            if (nt == 0) {
                #pragma unroll
                for (int ks = 0; ks < 3; ++ks) Af[ks] = pfP[ks];
            } else {
                const __hip_bfloat16* wp = wproj + (ch0 + lr) * CH + k0;
                #pragma unroll
                for (int ks = 0; ks < 3; ++ks) Af[ks] = ldfrag(wp + ks * 32);
            }
            f32x4 acc[2];
            acc[0] = (f32x4){0.f, 0.f, 0.f, 0.f};
            acc[1] = (f32x4){0.f, 0.f, 0.f, 0.f};
            #pragma unroll
            for (int ks = 0; ks < 3; ++ks) {
                acc[0] = MFMA(Af[ks], Bx2[0][ks], acc[0]);
                acc[1] = MFMA(Af[ks], Bx2[1][ks], acc[1]);
            }
            f32x4 pb4 = *(const f32x4*)(projb + ch0 + 4 * g);
            #pragma unroll
            for (int mi = 0; mi < 2; ++mi) {
                f32x4 x4 = (nt == 0) ? pfX[mi]
                                     : *(const f32x4*)(x + rowoff[mi] + ch0 + 4 * g);
                res[nt][mi] = acc[mi] + pb4 + x4;
            }
        }
    }

    // ---- Phase 4: LN2 stats (register res -> shuffle over g -> part LDS -> mu/rstd) ----
    {
        float s[2] = {0.f, 0.f}, s2[2] = {0.f, 0.f};
        #pragma unroll
        for (int mi = 0; mi < 2; ++mi)
            #pragma unroll
            for (int nt = 0; nt < 3; ++nt)
                #pragma unroll
                for (int j = 0; j < 4; ++j) {
                    float v = res[nt][mi][j];
                    s[mi] += v; s2[mi] += v * v;
                }
        #pragma unroll
        for (int mi = 0; mi < 2; ++mi) {
            s[mi]  += __shfl_xor(s[mi], 16);  s[mi]  += __shfl_xor(s[mi], 32);
            s2[mi] += __shfl_xor(s2[mi], 16); s2[mi] += __shfl_xor(s2[mi], 32);
            if (g == 0) {
                part[tokv[mi]][nh][0] = s[mi];
                part[tokv[mi]][nh][1] = s2[mi];
            }
        }
    }
    // prefetch LN2 gamma/beta (nt=0) across B5
    f32x4 pfW4, pfB4;
    pfW4 = *(const f32x4*)(n2w + nh * 48 + 4 * g);
    pfB4 = *(const f32x4*)(n2b + nh * 48 + 4 * g);
    __syncthreads();   // B5: partials complete (also: all Bx2 reads of XL done)
    float mu[2], rstd[2];
    #pragma unroll
    for (int mi = 0; mi < 2; ++mi) {
        float ts  = part[tokv[mi]][0][0] + part[tokv[mi]][1][0];
        float ts2 = part[tokv[mi]][0][1] + part[tokv[mi]][1][1];
        mu[mi] = ts * (1.f / CH);
        rstd[mi] = rsqrtf(ts2 * (1.f / CH) - mu[mi] * mu[mi] + 1e-5f);
    }
    // write LN2'd res into XL (rows 32mh.., ch 48nh.. — disjoint across waves)
    #pragma unroll
    for (int nt = 0; nt < 3; ++nt) {
        int ch0 = nh * 48 + nt * 16 + 4 * g;
        f32x4 w4 = (nt == 0) ? pfW4 : *(const f32x4*)(n2w + ch0);
        f32x4 b4 = (nt == 0) ? pfB4 : *(const f32x4*)(n2b + ch0);
        #pragma unroll
        for (int mi = 0; mi < 2; ++mi) {
            uint2 t;
            t.x = pk2((res[nt][mi][0] - mu[mi]) * rstd[mi] * w4[0] + b4[0],
                      (res[nt][mi][1] - mu[mi]) * rstd[mi] * w4[1] + b4[1]);
            t.y = pk2((res[nt][mi][2] - mu[mi]) * rstd[mi] * w4[2] + b4[2],
                      (res[nt][mi][3] - mu[mi]) * rstd[mi] * w4[3] + b4[3]);
            *(uint2*)&XL[tokv[mi]][ch0] = t;
        }
    }
    // prefetch fc1 weights (c=0, nl=w) across B6; pfC1[1] filled at end of chunk 0
    bf16x8 pfC1[2][3];
    {
        const __hip_bfloat16* wp = w1 + (w * 16 + lr) * CH + k0;
        #pragma unroll
        for (int ks = 0; ks < 3; ++ks) pfC1[0][ks] = ldfrag(wp + ks * 32);
    }
    __syncthreads();   // B6: XL = LN2'd res; part consumed; Kf/Vt dead -> Hs may overlay

    // ---- Phase 5: MLP, 2 k-chunks of 192 ----
    f32x4 acc2[3][2];
    #pragma unroll
    for (int nt = 0; nt < 3; ++nt)
        #pragma unroll
        for (int mi = 0; mi < 2; ++mi) acc2[nt][mi] = (f32x4){0.f, 0.f, 0.f, 0.f};

    #pragma unroll
    for (int c = 0; c < 2; ++c) {
        bf16x8 Bm[4][3];
        #pragma unroll
        for (int tt = 0; tt < 4; ++tt)
            #pragma unroll
            for (int ks = 0; ks < 3; ++ks)
                Bm[tt][ks] = ldfrag(&XL[tt * 16 + lr][ks * 32 + k0]);

        #pragma unroll
        for (int nn = 0; nn < 3; ++nn) {
            int nl = w + 4 * nn;
            int ncol = c * 192 + nl * 16;
            bf16x8 Af[3];
            if (nn == 0) {
                #pragma unroll
                for (int ks = 0; ks < 3; ++ks) Af[ks] = pfC1[c][ks];
            } else {
                const __hip_bfloat16* wp = w1 + (ncol + lr) * CH + k0;
                #pragma unroll
                for (int ks = 0; ks < 3; ++ks) Af[ks] = ldfrag(wp + ks * 32);
            }
            f32x4 acc[4];
            #pragma unroll
            for (int tt = 0; tt < 4; ++tt) acc[tt] = (f32x4){0.f, 0.f, 0.f, 0.f};
            #pragma unroll
            for (int ks = 0; ks < 3; ++ks)
                #pragma unroll
                for (int tt = 0; tt < 4; ++tt)
                    acc[tt] = MFMA(Af[ks], Bm[tt][ks], acc[tt]);
            f32x4 b4 = *(const f32x4*)(b1 + ncol + 4 * g);
            #pragma unroll
            for (int tt = 0; tt < 4; ++tt) {
                float gv[4];
                #pragma unroll
                for (int j = 0; j < 4; ++j) {
                    float v = acc[tt][j] + b4[j];
                    gv[j] = v * __builtin_amdgcn_rcpf(1.f + __expf(-1.702f * v));
                }
                uint2 t;
                t.x = pk2(gv[0], gv[1]);
                t.y = pk2(gv[2], gv[3]);
                *(uint2*)&Hs[tt * 16 + lr][nl * 16 + 4 * g] = t;
            }
        }
        // prefetch fc2 weights for k=0 across the fc1->fc2 barrier
        bf16x8 pfW2[3];
        #pragma unroll
        for (int nt = 0; nt < 3; ++nt)
            pfW2[nt] = ldfrag(w2 + (nh * 48 + nt * 16 + lr) * MLPH + c * 192 + k0);
        __syncthreads();   // fc1 chunk visible

        #pragma unroll
        for (int k = 0; k < 6; ++k) {
            bf16x8 h0 = ldfrag(&Hs[mh * 32 + lr][k * 32 + k0]);
            bf16x8 h1 = ldfrag(&Hs[mh * 32 + 16 + lr][k * 32 + k0]);
            #pragma unroll
            for (int nt = 0; nt < 3; ++nt) {
                bf16x8 Af = (k == 0) ? pfW2[nt]
                    : ldfrag(w2 + (nh * 48 + nt * 16 + lr) * MLPH + c * 192 + k * 32 + k0);
                acc2[nt][0] = MFMA(Af, h0, acc2[nt][0]);
                acc2[nt][1] = MFMA(Af, h1, acc2[nt][1]);
            }
        }
        if (c == 0) {
            // prefetch fc1 weights for chunk 1 across the fc2->fc1 barrier
            const __hip_bfloat16* wp = w1 + (192 + w * 16 + lr) * CH + k0;
            #pragma unroll
            for (int ks = 0; ks < 3; ++ks) pfC1[1][ks] = ldfrag(wp + ks * 32);
        }
        __syncthreads();   // fc2 reads done before next chunk overwrites Hs
    }

    // ---- Phase 6: single out write = res(regs) + mlp + bias ----
    #pragma unroll
    for (int nt = 0; nt < 3; ++nt) {
        f32x4 b4 = *(const f32x4*)(b2 + nh * 48 + nt * 16 + 4 * g);
        #pragma unroll
        for (int mi = 0; mi < 2; ++mi) {
            if (tokv[mi] < TOK) {
                size_t gi = rowoff[mi] + nh * 48 + nt * 16 + 4 * g;
                *(f32x4*)(out + gi) = res[nt][mi] + acc2[nt][mi] + b4;
            }
        }
    }
}

extern "C" void kernel_launch(void* const* d_in, const int* in_sizes, int n_in,
                              void* d_out, int out_size, void* d_ws, size_t ws_size,
                              hipStream_t stream) {
    const float* x     = (const float*)d_in[0];
    const float* n1w   = (const float*)d_in[1];
    const float* n1b   = (const float*)d_in[2];
    const float* qkvw  = (const float*)d_in[3];
    const float* qkvb  = (const float*)d_in[4];
    const float* relb  = (const float*)d_in[5];
    const float* projw = (const float*)d_in[6];
    const float* projb = (const float*)d_in[7];
    const float* n2w   = (const float*)d_in[8];
    const float* n2b   = (const float*)d_in[9];
    const float* fc1w  = (const float*)d_in[10];
    const float* fc1b  = (const float*)d_in[11];
    const float* fc2w  = (const float*)d_in[12];
    const float* fc2b  = (const float*)d_in[13];
    float* out = (float*)d_out;

    __hip_bfloat16* wbf = (__hip_bfloat16*)d_ws;
    float* btab = (float*)((char*)d_ws + 221184);
    const __hip_bfloat16* wqkv  = wbf;
    const __hip_bfloat16* wproj = wbf + 27648;
    const __hip_bfloat16* wfc1  = wbf + 36864;
    const __hip_bfloat16* wfc2  = wbf + 73728;

    prep<<<624, 256, 0, stream>>>(qkvw, projw, fc1w, fc2w, relb, wbf, btab);
    swin_fused<<<BATCH * 64, 256, 0, stream>>>(
        x, n1w, n1b, wqkv, qkvb, btab, wproj, projb,
        n2w, n2b, wfc1, fc1b, wfc2, fc2b, out);
}